// Round 9
// baseline (172.876 us; speedup 1.0000x reference)
//
#include <hip/hip_runtime.h>
#include <stdint.h>

#define LOG2E 1.4426950408889634f

typedef __bf16 v8bf __attribute__((ext_vector_type(8)));
typedef float v16f __attribute__((ext_vector_type(16)));

static constexpr int B = 4, N = 2048, FIN = 128, H = 4, DK = 32;
static constexpr int IT = N / 32;   // 64 i-tiles
static constexpr int PACK_BLOCKS = B * N * N / 1024;          // 16384
static constexpr int PREP_BLOCKS = (B * N * FIN + H * DK * FIN) / 256;  // 4160

__device__ __forceinline__ float exp2_fast(float x) {
#if __has_builtin(__builtin_amdgcn_exp2f)
  return __builtin_amdgcn_exp2f(x);
#else
  float r;
  asm("v_exp_f32 %0, %1" : "=v"(r) : "v"(x));
  return r;
#endif
}

__device__ __forceinline__ unsigned int bf16_rne(float f) {
  unsigned int u = __builtin_bit_cast(unsigned int, f);
  u += 0x7FFFu + ((u >> 16) & 1u);
  return u >> 16;
}

// ------- kernel 0 (merged): adj bit-pack + x->bf16 cast + wtb[h][d][f] bf16 -------
__global__ __launch_bounds__(256) void k_prep(const int* __restrict__ adj,
                                              const float* __restrict__ x,
                                              const float* __restrict__ W,
                                              unsigned int* __restrict__ adjb,
                                              unsigned short* __restrict__ xb,
                                              unsigned short* __restrict__ wtb) {
  int bid = blockIdx.x;
  int tid = threadIdx.x;
  if (bid < PACK_BLOCKS) {
    int wid = (bid * 256 + tid) >> 6;      // global wave id, 256 consecutive ints each
    int lane = tid & 63;
    const int* p = adj + (size_t)wid * 256 + lane;
    unsigned long long m0 = __ballot(p[0] != 0);
    unsigned long long m1 = __ballot(p[64] != 0);
    unsigned long long m2 = __ballot(p[128] != 0);
    unsigned long long m3 = __ballot(p[192] != 0);
    if (lane == 0) {
      uint4 v0 = {(unsigned)m0, (unsigned)(m0 >> 32), (unsigned)m1, (unsigned)(m1 >> 32)};
      uint4 v1 = {(unsigned)m2, (unsigned)(m2 >> 32), (unsigned)m3, (unsigned)(m3 >> 32)};
      uint4* dst = (uint4*)(adjb + (size_t)wid * 8);
      dst[0] = v0;
      dst[1] = v1;
    }
    return;
  }
  int idx = (bid - PACK_BLOCKS) * 256 + tid;
  constexpr int TX = B * N * FIN;          // 1048576
  if (idx < TX) {
    xb[idx] = (unsigned short)bf16_rne(x[idx]);
  } else {
    int j = idx - TX;                      // < H*DK*FIN = 16384
    int h = j >> 12, r = j & 4095, d = r >> 7, f = r & 127;
    wtb[j] = (unsigned short)bf16_rne(W[(h * FIN + f) * DK + d]);
  }
}

// ------- kernel 1: h projection via dual MFMA; h_frag (fragment order) + el/er2/fr2 -------
// er2 = exp2(er*log2e), fr2 = exp2(0.2*er*log2e): j-side softmax-product tables.
__global__ __launch_bounds__(256) void k_hproj(const unsigned short* __restrict__ xb,
                                               const unsigned short* __restrict__ wtb,
                                               const float* __restrict__ a,
                                               unsigned short* __restrict__ h_frag,
                                               float* __restrict__ el,
                                               float* __restrict__ er2,
                                               float* __restrict__ fr2) {
  int blk = blockIdx.x;
  int b = blk >> 6, it = blk & 63;
  int tid = threadIdx.x;
  int head = tid >> 6, lane = tid & 63;
  int lrow = lane & 31, kh = lane >> 5;
  int bh = b * H + head;
  int n = it * 32 + lrow;
  const unsigned short* xp = xb + (b * N + n) * FIN + kh * 8;
  const unsigned short* wp = wtb + (head * DK + lrow) * FIN + kh * 8;
  v16f acc = {};    // D[d][n], col=n=lrow
  v16f accd = {};   // D[n][d], col=d=lrow
#pragma unroll
  for (int s = 0; s < FIN / 16; ++s) {
    v8bf av = __builtin_bit_cast(v8bf, *(const int4*)(wp + s * 16));
    v8bf bv = __builtin_bit_cast(v8bf, *(const int4*)(xp + s * 16));
    acc = __builtin_amdgcn_mfma_f32_32x32x16_bf16(av, bv, acc, 0, 0, 0);
    accd = __builtin_amdgcn_mfma_f32_32x32x16_bf16(bv, av, accd, 0, 0, 0);
  }
  // h_frag: thread holds h[n = (r&3)+8*(r>>2)+4*kh][d = lrow] for r=0..15.
  {
    unsigned w[8];
#pragma unroll
    for (int i = 0; i < 8; ++i)
      w[i] = bf16_rne(accd[2 * i]) | (bf16_rne(accd[2 * i + 1]) << 16);
    unsigned short* fp = h_frag + (((size_t)bh * 128 + it * 2) * 64 + lane) * 8;
    int4 v0 = {(int)w[0], (int)w[1], (int)w[2], (int)w[3]};
    int4 v1 = {(int)w[4], (int)w[5], (int)w[6], (int)w[7]};
    *(int4*)fp = v0;
    *(int4*)(fp + 512) = v1;   // next jblk: +64 lanes * 8 shorts
  }
  float pel = 0.f, per = 0.f;
#pragma unroll
  for (int r = 0; r < 16; ++r) {
    int d = (r & 3) + 8 * (r >> 2) + 4 * kh;   // C/D row mapping (32x32 bf16)
    float hv = acc[r];
    pel = fmaf(hv, a[head * 2 * DK + d], pel);
    per = fmaf(hv, a[head * 2 * DK + DK + d], per);
  }
  pel += __shfl_xor(pel, 32);
  per += __shfl_xor(per, 32);
  if (kh == 0) {
    el[bh * N + n] = pel * LOG2E;
    float t = per * LOG2E;
    er2[bh * N + n] = exp2_fast(t);
    fr2[bh * N + n] = exp2_fast(0.2f * t);
  }
}

// ---------------- kernel 2: fused attention over a j-HALF ----------------
// grid = B*IT*2 = 512 (exactly 2 blocks/CU, fully resident, single round);
// block = 512 threads = 8 waves = (kq 0..1) x (head 0..3); each wave sweeps
// 512 j = 32 iters as an outer p-loop (unroll 1, blocks address hoisting /
// keeps adjacency statically indexed) around the proven 16-iter unrolled body.
// Inner loop exp-free: exp2(max(t,.2t)) == max(Eli*er2[j], Fli*fr2[j]).
// launch_bounds(512,4): 128-VGPR budget, no spill (r7 lesson).
__global__ __launch_bounds__(512, 4) void k_attn(const unsigned int* __restrict__ adjb,
                                                 const unsigned short* __restrict__ h_frag,
                                                 const float* __restrict__ el,
                                                 const float* __restrict__ er2,
                                                 const float* __restrict__ fr2,
                                                 float* __restrict__ pnum,
                                                 float* __restrict__ pden) {
  // 32KB, dual-role (barrier-separated): stage stg[t][head][j-local] during the
  // loop, partial slices part[kq][head][i*32+d] after it.
  __shared__ __align__(16) float smem[2][H][1024];
  __shared__ float lsh2[2][H][32];
  int blk = blockIdx.x;                 // 0..511
  int bit = blk >> 1, jh = blk & 1;
  int b = bit >> 6, it = bit & 63;
  int tid = threadIdx.x;
  int wave = tid >> 6;
  int head = wave & 3, kq = wave >> 2;
  int lane = tid & 63, lrow = lane & 31, kh = lane >> 5;
  int ig = it * 32 + lrow, bh = b * H + head;

  // stage er2/fr2 for this j-half, all 4 heads: 8192 floats, 4x float4/thread
#pragma unroll
  for (int i = 0; i < 4; ++i) {
    int q = tid + 512 * i;                    // float4 index, coalesced
    int t = q >> 10, hh = (q >> 8) & 3, jl = (q & 255) * 4;
    const float* src = (t ? fr2 : er2) + (b * H + hh) * N + jh * 1024 + jl;
    *(float4*)&smem[t][hh][jl] = *(const float4*)src;
  }

  float eli = el[bh * N + ig];
  float Eli = exp2_fast(eli);
  float Fli = exp2_fast(0.2f * eli);

  // wave's j-window: jh*1024 + kq*512, walked in 2 passes of 256 j.
  // coalesced fragment pointer: jblk = jh*64 + kq*32 + p*16 + s; 512 shorts/jblk
  const unsigned short* hp =
      h_frag + (((size_t)bh * 128 + jh * 64 + kq * 32) * 64 + lane) * 8;
  const unsigned int* abp0 = adjb + (size_t)(b * N + ig) * 64 + jh * 32 + kq * 16;
  int shkh = kh * 4;

  // h prefetch, 2 deep, live across passes (pass0 tail prefetches pass1 head)
  int4 hreg0 = *(const int4*)hp;
  int4 hreg1 = *(const int4*)(hp + 512);

  __syncthreads();   // stage visible

  v16f acc = {};
  float lsum = 0.f;
#pragma unroll 1
  for (int p = 0; p < 2; ++p) {
    const uint4* abp = (const uint4*)(abp0 + p * 8);
    uint4 ab0 = abp[0], ab1 = abp[1];
    unsigned adw[8] = {ab0.x, ab0.y, ab0.z, ab0.w, ab1.x, ab1.y, ab1.z, ab1.w};
    const unsigned short* hpp = hp + p * 8192;       // p*16 jblks * 512
    int jlb = kq * 512 + p * 256 + 4 * kh;           // j-local base (k-permuted)
    float4 Ea = *(const float4*)&smem[0][head][jlb];
    float4 Eb = *(const float4*)&smem[0][head][jlb + 8];
    float4 Fa = *(const float4*)&smem[1][head][jlb];
    float4 Fb = *(const float4*)&smem[1][head][jlb + 8];
#pragma unroll
    for (int s = 0; s < 16; ++s) {
      int4 hb = (s & 1) ? hreg1 : hreg0;
      if (p == 0 || s + 2 < 16) {          // pass1 tail: nothing left to prefetch
        int4 nv = *(const int4*)(hpp + (s + 2) * 512);
        if (s & 1) hreg1 = nv; else hreg0 = nv;
      }
      float4 ea = Ea, eb = Eb, fa = Fa, fb = Fb;
      if (s + 1 < 16) {
        Ea = *(const float4*)&smem[0][head][jlb + (s + 1) * 16];
        Eb = *(const float4*)&smem[0][head][jlb + (s + 1) * 16 + 8];
        Fa = *(const float4*)&smem[1][head][jlb + (s + 1) * 16];
        Fb = *(const float4*)&smem[1][head][jlb + (s + 1) * 16 + 8];
      }
      // bits for slots e: j-offset = s*16 + 4*kh + (e&3) + 8*(e>>2)
      unsigned mb = (adw[s >> 1] >> (((s & 1) * 16) + shkh)) & 0xF0Fu;
      float ev[8] = {ea.x, ea.y, ea.z, ea.w, eb.x, eb.y, eb.z, eb.w};
      float fv[8] = {fa.x, fa.y, fa.z, fa.w, fb.x, fb.y, fb.z, fb.w};
      unsigned ub[8];
#pragma unroll
      for (int k = 0; k < 8; ++k) {
        float pv = fmaxf(Eli * ev[k], Fli * fv[k]);   // leaky-relu+exp, product form
        unsigned u = __builtin_bit_cast(unsigned, pv) & 0xFFFF0000u;
        // compile-time constant bit (k unrolled): {1,2,4,8,0x100,0x200,0x400,0x800}
        u = (mb & (1u << ((k & 3) + 8 * (k >> 2)))) ? u : 0u;
        ub[k] = u;
        lsum += __builtin_bit_cast(float, u); // truncated value: num/den consistent
      }
      unsigned u0 = __builtin_amdgcn_perm(ub[1], ub[0], 0x07060302u);
      unsigned u1 = __builtin_amdgcn_perm(ub[3], ub[2], 0x07060302u);
      unsigned u2 = __builtin_amdgcn_perm(ub[5], ub[4], 0x07060302u);
      unsigned u3 = __builtin_amdgcn_perm(ub[7], ub[6], 0x07060302u);
      uint4 au = {u0, u1, u2, u3};
      v8bf av = __builtin_bit_cast(v8bf, au);
      v8bf hv = __builtin_bit_cast(v8bf, hb);
      acc = __builtin_amdgcn_mfma_f32_32x32x16_bf16(av, hv, acc, 0, 0, 0);
    }
  }

  lsum += __shfl_xor(lsum, 32);
  if (lane < 32) lsh2[kq][head][lane] = lsum;   // separate array: safe pre-barrier

  __syncthreads();   // all stage reads done before smem is reused as partials

#pragma unroll
  for (int r = 0; r < 16; ++r) {
    int rowl = (r & 3) + 8 * (r >> 2) + 4 * kh;   // i-row within tile
    smem[kq][head][rowl * 32 + lrow] = acc[r];    // private slice: plain store
  }
  __syncthreads();

  // combine 2 kq slices; 4096 partials / 512 threads = 8 floats (2x float4) each
  int e = tid * 8;
  int rh = e >> 10, rr = e & 1023;
  float4 a0 = *(const float4*)&smem[0][rh][rr];
  float4 a1 = *(const float4*)&smem[1][rh][rr];
  float4 b0 = *(const float4*)&smem[0][rh][rr + 4];
  float4 b1 = *(const float4*)&smem[1][rh][rr + 4];
  float4 s0 = {a0.x + a1.x, a0.y + a1.y, a0.z + a1.z, a0.w + a1.w};
  float4 s1 = {b0.x + b1.x, b0.y + b1.y, b0.z + b1.z, b0.w + b1.w};
  *(float4*)&pnum[(size_t)blk * 4096 + e] = s0;
  *(float4*)&pnum[(size_t)blk * 4096 + e + 4] = s1;
  if (tid < 128) {
    pden[blk * 128 + tid] = lsh2[0][tid >> 5][tid & 31] + lsh2[1][tid >> 5][tid & 31];
  }
}

// ---------------- kernel 3: combine j-halves + normalize ----------------
__global__ __launch_bounds__(1024) void k_final(const float* __restrict__ pnum,
                                                const float* __restrict__ pden,
                                                float* __restrict__ out) {
  int bit = blockIdx.x;            // 0..255 = (b, it)
  int b = bit >> 6, it = bit & 63;
  int tid = threadIdx.x;
  int e = tid * 4;
  int rh = e >> 10, ri = (e >> 5) & 31, rd = e & 31;
  size_t p0 = (size_t)(bit * 2) * 4096 + e;
  float4 n0 = *(const float4*)&pnum[p0];
  float4 n1 = *(const float4*)&pnum[p0 + 4096];
  float d = pden[bit * 2 * 128 + rh * 32 + ri] + pden[(bit * 2 + 1) * 128 + rh * 32 + ri];
  float inv = 1.0f / d;
  float4 o;
  o.x = (n0.x + n1.x) * inv;
  o.y = (n0.y + n1.y) * inv;
  o.z = (n0.z + n1.z) * inv;
  o.w = (n0.w + n1.w) * inv;
  *(float4*)&out[(size_t)((b * H + rh) * N + it * 32 + ri) * DK + rd] = o;
}

extern "C" void kernel_launch(void* const* d_in, const int* in_sizes, int n_in,
                              void* d_out, int out_size, void* d_ws, size_t ws_size,
                              hipStream_t stream) {
  const float* x = (const float*)d_in[0];
  const int* adj = (const int*)d_in[1];
  const float* W = (const float*)d_in[2];
  const float* a = (const float*)d_in[3];
  float* out = (float*)d_out;
  char* ws = (char*)d_ws;

  unsigned short* h_frag = (unsigned short*)(ws);          // 2 MB   [B*H][128 jblk][64][8]
  float* el = (float*)(ws + 0x200000);                     // 128 KB
  float* er2 = (float*)(ws + 0x220000);                    // 128 KB exp2 table
  float* fr2 = (float*)(ws + 0x240000);                    // 128 KB exp2(0.2) table
  unsigned short* wtb = (unsigned short*)(ws + 0x260000);  // 32 KB
  unsigned int* adjb = (unsigned int*)(ws + 0x270000);     // 2 MB bitmask
  unsigned short* xb = (unsigned short*)(ws + 0x470000);   // 2 MB
  float* pnum = (float*)(ws + 0x670000);                   // 8 MB   [512][4096]
  float* pden = (float*)(ws + 0xE70000);                   // 256 KB [512][128]
  // total ~15 MB

  hipLaunchKernelGGL(k_prep, dim3(PACK_BLOCKS + PREP_BLOCKS), dim3(256), 0, stream,
                     adj, x, W, adjb, xb, wtb);
  hipLaunchKernelGGL(k_hproj, dim3(B * IT), dim3(256), 0, stream, xb, wtb, a, h_frag, el, er2, fr2);
  hipLaunchKernelGGL(k_attn, dim3(B * IT * 2), dim3(512), 0, stream, adjb, h_frag, el, er2, fr2,
                     pnum, pden);
  hipLaunchKernelGGL(k_final, dim3(B * IT), dim3(1024), 0, stream, pnum, pden, out);
}

// Round 10
// 127.945 us; speedup vs baseline: 1.3512x; 1.3512x over previous
//
#include <hip/hip_runtime.h>
#include <stdint.h>

#define LOG2E 1.4426950408889634f

typedef __bf16 v8bf __attribute__((ext_vector_type(8)));
typedef float v16f __attribute__((ext_vector_type(16)));

static constexpr int B = 4, N = 2048, FIN = 128, H = 4, DK = 32;
static constexpr int IT = N / 32;   // 64 i-tiles
static constexpr int PACK_BLOCKS = B * N * N / 1024;          // 16384
static constexpr int PREP_BLOCKS = (B * N * FIN + H * DK * FIN) / 256;  // 4160

__device__ __forceinline__ float exp2_fast(float x) {
#if __has_builtin(__builtin_amdgcn_exp2f)
  return __builtin_amdgcn_exp2f(x);
#else
  float r;
  asm("v_exp_f32 %0, %1" : "=v"(r) : "v"(x));
  return r;
#endif
}

__device__ __forceinline__ unsigned int bf16_rne(float f) {
  unsigned int u = __builtin_bit_cast(unsigned int, f);
  u += 0x7FFFu + ((u >> 16) & 1u);
  return u >> 16;
}

// ------- kernel 0 (merged): adj bit-pack + x->bf16 cast + wtb[h][d][f] bf16 -------
__global__ __launch_bounds__(256) void k_prep(const int* __restrict__ adj,
                                              const float* __restrict__ x,
                                              const float* __restrict__ W,
                                              unsigned int* __restrict__ adjb,
                                              unsigned short* __restrict__ xb,
                                              unsigned short* __restrict__ wtb) {
  int bid = blockIdx.x;
  int tid = threadIdx.x;
  if (bid < PACK_BLOCKS) {
    int wid = (bid * 256 + tid) >> 6;      // global wave id, 256 consecutive ints each
    int lane = tid & 63;
    const int* p = adj + (size_t)wid * 256 + lane;
    unsigned long long m0 = __ballot(p[0] != 0);
    unsigned long long m1 = __ballot(p[64] != 0);
    unsigned long long m2 = __ballot(p[128] != 0);
    unsigned long long m3 = __ballot(p[192] != 0);
    if (lane == 0) {
      uint4 v0 = {(unsigned)m0, (unsigned)(m0 >> 32), (unsigned)m1, (unsigned)(m1 >> 32)};
      uint4 v1 = {(unsigned)m2, (unsigned)(m2 >> 32), (unsigned)m3, (unsigned)(m3 >> 32)};
      uint4* dst = (uint4*)(adjb + (size_t)wid * 8);
      dst[0] = v0;
      dst[1] = v1;
    }
    return;
  }
  int idx = (bid - PACK_BLOCKS) * 256 + tid;
  constexpr int TX = B * N * FIN;          // 1048576
  if (idx < TX) {
    xb[idx] = (unsigned short)bf16_rne(x[idx]);
  } else {
    int j = idx - TX;                      // < H*DK*FIN = 16384
    int h = j >> 12, r = j & 4095, d = r >> 7, f = r & 127;
    wtb[j] = (unsigned short)bf16_rne(W[(h * FIN + f) * DK + d]);
  }
}

// ------- kernel 1: h projection via dual MFMA; h_frag (fragment order) + el/er2/fr2 -------
// er2 = exp2(er*log2e), fr2 = exp2(0.2*er*log2e): j-side softmax-product tables.
__global__ __launch_bounds__(256) void k_hproj(const unsigned short* __restrict__ xb,
                                               const unsigned short* __restrict__ wtb,
                                               const float* __restrict__ a,
                                               unsigned short* __restrict__ h_frag,
                                               float* __restrict__ el,
                                               float* __restrict__ er2,
                                               float* __restrict__ fr2) {
  int blk = blockIdx.x;
  int b = blk >> 6, it = blk & 63;
  int tid = threadIdx.x;
  int head = tid >> 6, lane = tid & 63;
  int lrow = lane & 31, kh = lane >> 5;
  int bh = b * H + head;
  int n = it * 32 + lrow;
  const unsigned short* xp = xb + (b * N + n) * FIN + kh * 8;
  const unsigned short* wp = wtb + (head * DK + lrow) * FIN + kh * 8;
  v16f acc = {};    // D[d][n], col=n=lrow
  v16f accd = {};   // D[n][d], col=d=lrow
#pragma unroll
  for (int s = 0; s < FIN / 16; ++s) {
    v8bf av = __builtin_bit_cast(v8bf, *(const int4*)(wp + s * 16));
    v8bf bv = __builtin_bit_cast(v8bf, *(const int4*)(xp + s * 16));
    acc = __builtin_amdgcn_mfma_f32_32x32x16_bf16(av, bv, acc, 0, 0, 0);
    accd = __builtin_amdgcn_mfma_f32_32x32x16_bf16(bv, av, accd, 0, 0, 0);
  }
  // h_frag: thread holds h[n = (r&3)+8*(r>>2)+4*kh][d = lrow] for r=0..15.
  {
    unsigned w[8];
#pragma unroll
    for (int i = 0; i < 8; ++i)
      w[i] = bf16_rne(accd[2 * i]) | (bf16_rne(accd[2 * i + 1]) << 16);
    unsigned short* fp = h_frag + (((size_t)bh * 128 + it * 2) * 64 + lane) * 8;
    int4 v0 = {(int)w[0], (int)w[1], (int)w[2], (int)w[3]};
    int4 v1 = {(int)w[4], (int)w[5], (int)w[6], (int)w[7]};
    *(int4*)fp = v0;
    *(int4*)(fp + 512) = v1;   // next jblk: +64 lanes * 8 shorts
  }
  float pel = 0.f, per = 0.f;
#pragma unroll
  for (int r = 0; r < 16; ++r) {
    int d = (r & 3) + 8 * (r >> 2) + 4 * kh;   // C/D row mapping (32x32 bf16)
    float hv = acc[r];
    pel = fmaf(hv, a[head * 2 * DK + d], pel);
    per = fmaf(hv, a[head * 2 * DK + DK + d], per);
  }
  pel += __shfl_xor(pel, 32);
  per += __shfl_xor(per, 32);
  if (kh == 0) {
    el[bh * N + n] = pel * LOG2E;
    float t = per * LOG2E;
    er2[bh * N + n] = exp2_fast(t);
    fr2[bh * N + n] = exp2_fast(0.2f * t);
  }
}

// ---------------- kernel 2: fused attention over a j-HALF ----------------
// grid = B*IT*2 = 512 (exactly 2 blocks/CU, fully resident, single round);
// block = 512 threads = 8 waves = (kq 0..1) x (head 0..3); each wave sweeps
// 512 j = 32 iters as an outer p-loop around the 16-iter unrolled body.
// launch_bounds(512, 2): r9's (512,4) imposed a 64-VGPR cap -> 460B/thread
// scratch spill (WRITE_SIZE 120MB). This body needs ~100 VGPR; (512,2) caps
// at >=128 under either arg2 interpretation, so the allocator fits it without
// spilling and actual usage <=128 still yields 2 resident blocks/CU.
// E/F LDS reads are plain per-iteration loads (compiler pipelines LDS within
// the unrolled body; manual rotation only added 16 live VGPRs).
__global__ __launch_bounds__(512, 2) void k_attn(const unsigned int* __restrict__ adjb,
                                                 const unsigned short* __restrict__ h_frag,
                                                 const float* __restrict__ el,
                                                 const float* __restrict__ er2,
                                                 const float* __restrict__ fr2,
                                                 float* __restrict__ pnum,
                                                 float* __restrict__ pden) {
  // 32KB, dual-role (barrier-separated): stage stg[t][head][j-local] during the
  // loop, partial slices part[kq][head][i*32+d] after it.
  __shared__ __align__(16) float smem[2][H][1024];
  __shared__ float lsh2[2][H][32];
  int blk = blockIdx.x;                 // 0..511
  int bit = blk >> 1, jh = blk & 1;
  int b = bit >> 6, it = bit & 63;
  int tid = threadIdx.x;
  int wave = tid >> 6;
  int head = wave & 3, kq = wave >> 2;
  int lane = tid & 63, lrow = lane & 31, kh = lane >> 5;
  int ig = it * 32 + lrow, bh = b * H + head;

  // stage er2/fr2 for this j-half, all 4 heads: 8192 floats, 4x float4/thread
#pragma unroll
  for (int i = 0; i < 4; ++i) {
    int q = tid + 512 * i;                    // float4 index, coalesced
    int t = q >> 10, hh = (q >> 8) & 3, jl = (q & 255) * 4;
    const float* src = (t ? fr2 : er2) + (b * H + hh) * N + jh * 1024 + jl;
    *(float4*)&smem[t][hh][jl] = *(const float4*)src;
  }

  float eli = el[bh * N + ig];
  float Eli = exp2_fast(eli);
  float Fli = exp2_fast(0.2f * eli);

  // wave's j-window: jh*1024 + kq*512, walked in 2 passes of 256 j.
  // coalesced fragment pointer: jblk = jh*64 + kq*32 + p*16 + s; 512 shorts/jblk
  const unsigned short* hp =
      h_frag + (((size_t)bh * 128 + jh * 64 + kq * 32) * 64 + lane) * 8;
  const unsigned int* abp0 = adjb + (size_t)(b * N + ig) * 64 + jh * 32 + kq * 16;
  int shkh = kh * 4;

  // h prefetch, 2 deep, live across passes (pass0 tail prefetches pass1 head)
  int4 hreg0 = *(const int4*)hp;
  int4 hreg1 = *(const int4*)(hp + 512);

  __syncthreads();   // stage visible

  v16f acc = {};
  float lsum = 0.f;
#pragma unroll 1
  for (int p = 0; p < 2; ++p) {
    const uint4* abp = (const uint4*)(abp0 + p * 8);
    uint4 ab0 = abp[0], ab1 = abp[1];
    unsigned adw[8] = {ab0.x, ab0.y, ab0.z, ab0.w, ab1.x, ab1.y, ab1.z, ab1.w};
    const unsigned short* hpp = hp + p * 8192;       // p*16 jblks * 512
    int jlb = kq * 512 + p * 256 + 4 * kh;           // j-local base (k-permuted)
#pragma unroll
    for (int s = 0; s < 16; ++s) {
      int4 hb = (s & 1) ? hreg1 : hreg0;
      if (p == 0 || s + 2 < 16) {          // pass1 tail: nothing left to prefetch
        int4 nv = *(const int4*)(hpp + (s + 2) * 512);
        if (s & 1) hreg1 = nv; else hreg0 = nv;
      }
      float4 ea = *(const float4*)&smem[0][head][jlb + s * 16];
      float4 eb = *(const float4*)&smem[0][head][jlb + s * 16 + 8];
      float4 fa = *(const float4*)&smem[1][head][jlb + s * 16];
      float4 fb = *(const float4*)&smem[1][head][jlb + s * 16 + 8];
      // bits for slots e: j-offset = s*16 + 4*kh + (e&3) + 8*(e>>2)
      unsigned mb = (adw[s >> 1] >> (((s & 1) * 16) + shkh)) & 0xF0Fu;
      float ev[8] = {ea.x, ea.y, ea.z, ea.w, eb.x, eb.y, eb.z, eb.w};
      float fv[8] = {fa.x, fa.y, fa.z, fa.w, fb.x, fb.y, fb.z, fb.w};
      unsigned ub[8];
#pragma unroll
      for (int k = 0; k < 8; ++k) {
        float pv = fmaxf(Eli * ev[k], Fli * fv[k]);   // leaky-relu+exp, product form
        unsigned u = __builtin_bit_cast(unsigned, pv) & 0xFFFF0000u;
        // compile-time constant bit (k unrolled): {1,2,4,8,0x100,0x200,0x400,0x800}
        u = (mb & (1u << ((k & 3) + 8 * (k >> 2)))) ? u : 0u;
        ub[k] = u;
        lsum += __builtin_bit_cast(float, u); // truncated value: num/den consistent
      }
      unsigned u0 = __builtin_amdgcn_perm(ub[1], ub[0], 0x07060302u);
      unsigned u1 = __builtin_amdgcn_perm(ub[3], ub[2], 0x07060302u);
      unsigned u2 = __builtin_amdgcn_perm(ub[5], ub[4], 0x07060302u);
      unsigned u3 = __builtin_amdgcn_perm(ub[7], ub[6], 0x07060302u);
      uint4 au = {u0, u1, u2, u3};
      v8bf av = __builtin_bit_cast(v8bf, au);
      v8bf hv = __builtin_bit_cast(v8bf, hb);
      acc = __builtin_amdgcn_mfma_f32_32x32x16_bf16(av, hv, acc, 0, 0, 0);
    }
  }

  lsum += __shfl_xor(lsum, 32);
  if (lane < 32) lsh2[kq][head][lane] = lsum;   // separate array: safe pre-barrier

  __syncthreads();   // all stage reads done before smem is reused as partials

#pragma unroll
  for (int r = 0; r < 16; ++r) {
    int rowl = (r & 3) + 8 * (r >> 2) + 4 * kh;   // i-row within tile
    smem[kq][head][rowl * 32 + lrow] = acc[r];    // private slice: plain store
  }
  __syncthreads();

  // combine 2 kq slices; 4096 partials / 512 threads = 8 floats (2x float4) each
  int e = tid * 8;
  int rh = e >> 10, rr = e & 1023;
  float4 a0 = *(const float4*)&smem[0][rh][rr];
  float4 a1 = *(const float4*)&smem[1][rh][rr];
  float4 b0 = *(const float4*)&smem[0][rh][rr + 4];
  float4 b1 = *(const float4*)&smem[1][rh][rr + 4];
  float4 s0 = {a0.x + a1.x, a0.y + a1.y, a0.z + a1.z, a0.w + a1.w};
  float4 s1 = {b0.x + b1.x, b0.y + b1.y, b0.z + b1.z, b0.w + b1.w};
  *(float4*)&pnum[(size_t)blk * 4096 + e] = s0;
  *(float4*)&pnum[(size_t)blk * 4096 + e + 4] = s1;
  if (tid < 128) {
    pden[blk * 128 + tid] = lsh2[0][tid >> 5][tid & 31] + lsh2[1][tid >> 5][tid & 31];
  }
}

// ---------------- kernel 3: combine j-halves + normalize ----------------
__global__ __launch_bounds__(1024) void k_final(const float* __restrict__ pnum,
                                                const float* __restrict__ pden,
                                                float* __restrict__ out) {
  int bit = blockIdx.x;            // 0..255 = (b, it)
  int b = bit >> 6, it = bit & 63;
  int tid = threadIdx.x;
  int e = tid * 4;
  int rh = e >> 10, ri = (e >> 5) & 31, rd = e & 31;
  size_t p0 = (size_t)(bit * 2) * 4096 + e;
  float4 n0 = *(const float4*)&pnum[p0];
  float4 n1 = *(const float4*)&pnum[p0 + 4096];
  float d = pden[bit * 2 * 128 + rh * 32 + ri] + pden[(bit * 2 + 1) * 128 + rh * 32 + ri];
  float inv = 1.0f / d;
  float4 o;
  o.x = (n0.x + n1.x) * inv;
  o.y = (n0.y + n1.y) * inv;
  o.z = (n0.z + n1.z) * inv;
  o.w = (n0.w + n1.w) * inv;
  *(float4*)&out[(size_t)((b * H + rh) * N + it * 32 + ri) * DK + rd] = o;
}

extern "C" void kernel_launch(void* const* d_in, const int* in_sizes, int n_in,
                              void* d_out, int out_size, void* d_ws, size_t ws_size,
                              hipStream_t stream) {
  const float* x = (const float*)d_in[0];
  const int* adj = (const int*)d_in[1];
  const float* W = (const float*)d_in[2];
  const float* a = (const float*)d_in[3];
  float* out = (float*)d_out;
  char* ws = (char*)d_ws;

  unsigned short* h_frag = (unsigned short*)(ws);          // 2 MB   [B*H][128 jblk][64][8]
  float* el = (float*)(ws + 0x200000);                     // 128 KB
  float* er2 = (float*)(ws + 0x220000);                    // 128 KB exp2 table
  float* fr2 = (float*)(ws + 0x240000);                    // 128 KB exp2(0.2) table
  unsigned short* wtb = (unsigned short*)(ws + 0x260000);  // 32 KB
  unsigned int* adjb = (unsigned int*)(ws + 0x270000);     // 2 MB bitmask
  unsigned short* xb = (unsigned short*)(ws + 0x470000);   // 2 MB
  float* pnum = (float*)(ws + 0x670000);                   // 8 MB   [512][4096]
  float* pden = (float*)(ws + 0xE70000);                   // 256 KB [512][128]
  // total ~15 MB

  hipLaunchKernelGGL(k_prep, dim3(PACK_BLOCKS + PREP_BLOCKS), dim3(256), 0, stream,
                     adj, x, W, adjb, xb, wtb);
  hipLaunchKernelGGL(k_hproj, dim3(B * IT), dim3(256), 0, stream, xb, wtb, a, h_frag, el, er2, fr2);
  hipLaunchKernelGGL(k_attn, dim3(B * IT * 2), dim3(512), 0, stream, adjb, h_frag, el, er2, fr2,
                     pnum, pden);
  hipLaunchKernelGGL(k_final, dim3(B * IT), dim3(1024), 0, stream, pnum, pden, out);
}

// Round 11
// 127.526 us; speedup vs baseline: 1.3556x; 1.0033x over previous
//
#include <hip/hip_runtime.h>
#include <stdint.h>

#define LOG2E 1.4426950408889634f

typedef __bf16 v8bf __attribute__((ext_vector_type(8)));
typedef float v16f __attribute__((ext_vector_type(16)));

static constexpr int B = 4, N = 2048, FIN = 128, H = 4, DK = 32;
static constexpr int IT = N / 32;   // 64 i-tiles
static constexpr int PACK_BLOCKS = B * N * N / 1024;          // 16384
static constexpr int PREP_BLOCKS = (B * N * FIN + H * DK * FIN) / 256;  // 4160

__device__ __forceinline__ float exp2_fast(float x) {
#if __has_builtin(__builtin_amdgcn_exp2f)
  return __builtin_amdgcn_exp2f(x);
#else
  float r;
  asm("v_exp_f32 %0, %1" : "=v"(r) : "v"(x));
  return r;
#endif
}

__device__ __forceinline__ unsigned int bf16_rne(float f) {
  unsigned int u = __builtin_bit_cast(unsigned int, f);
  u += 0x7FFFu + ((u >> 16) & 1u);
  return u >> 16;
}

// ------- kernel 0 (merged): adj bit-pack + x->bf16 cast + wtb[h][d][f] bf16 -------
__global__ __launch_bounds__(256) void k_prep(const int* __restrict__ adj,
                                              const float* __restrict__ x,
                                              const float* __restrict__ W,
                                              unsigned int* __restrict__ adjb,
                                              unsigned short* __restrict__ xb,
                                              unsigned short* __restrict__ wtb) {
  int bid = blockIdx.x;
  int tid = threadIdx.x;
  if (bid < PACK_BLOCKS) {
    int wid = (bid * 256 + tid) >> 6;      // global wave id, 256 consecutive ints each
    int lane = tid & 63;
    const int* p = adj + (size_t)wid * 256 + lane;
    unsigned long long m0 = __ballot(p[0] != 0);
    unsigned long long m1 = __ballot(p[64] != 0);
    unsigned long long m2 = __ballot(p[128] != 0);
    unsigned long long m3 = __ballot(p[192] != 0);
    if (lane == 0) {
      uint4 v0 = {(unsigned)m0, (unsigned)(m0 >> 32), (unsigned)m1, (unsigned)(m1 >> 32)};
      uint4 v1 = {(unsigned)m2, (unsigned)(m2 >> 32), (unsigned)m3, (unsigned)(m3 >> 32)};
      uint4* dst = (uint4*)(adjb + (size_t)wid * 8);
      dst[0] = v0;
      dst[1] = v1;
    }
    return;
  }
  int idx = (bid - PACK_BLOCKS) * 256 + tid;
  constexpr int TX = B * N * FIN;          // 1048576
  if (idx < TX) {
    xb[idx] = (unsigned short)bf16_rne(x[idx]);
  } else {
    int j = idx - TX;                      // < H*DK*FIN = 16384
    int h = j >> 12, r = j & 4095, d = r >> 7, f = r & 127;
    wtb[j] = (unsigned short)bf16_rne(W[(h * FIN + f) * DK + d]);
  }
}

// ------- kernel 1: h projection via dual MFMA; h_frag (fragment order) + el/er2/fr2 -------
// er2 = exp2(er*log2e), fr2 = exp2(0.2*er*log2e): j-side softmax-product tables.
__global__ __launch_bounds__(256) void k_hproj(const unsigned short* __restrict__ xb,
                                               const unsigned short* __restrict__ wtb,
                                               const float* __restrict__ a,
                                               unsigned short* __restrict__ h_frag,
                                               float* __restrict__ el,
                                               float* __restrict__ er2,
                                               float* __restrict__ fr2) {
  int blk = blockIdx.x;
  int b = blk >> 6, it = blk & 63;
  int tid = threadIdx.x;
  int head = tid >> 6, lane = tid & 63;
  int lrow = lane & 31, kh = lane >> 5;
  int bh = b * H + head;
  int n = it * 32 + lrow;
  const unsigned short* xp = xb + (b * N + n) * FIN + kh * 8;
  const unsigned short* wp = wtb + (head * DK + lrow) * FIN + kh * 8;
  v16f acc = {};    // D[d][n], col=n=lrow
  v16f accd = {};   // D[n][d], col=d=lrow
#pragma unroll
  for (int s = 0; s < FIN / 16; ++s) {
    v8bf av = __builtin_bit_cast(v8bf, *(const int4*)(wp + s * 16));
    v8bf bv = __builtin_bit_cast(v8bf, *(const int4*)(xp + s * 16));
    acc = __builtin_amdgcn_mfma_f32_32x32x16_bf16(av, bv, acc, 0, 0, 0);
    accd = __builtin_amdgcn_mfma_f32_32x32x16_bf16(bv, av, accd, 0, 0, 0);
  }
  // h_frag: thread holds h[n = (r&3)+8*(r>>2)+4*kh][d = lrow] for r=0..15.
  {
    unsigned w[8];
#pragma unroll
    for (int i = 0; i < 8; ++i)
      w[i] = bf16_rne(accd[2 * i]) | (bf16_rne(accd[2 * i + 1]) << 16);
    unsigned short* fp = h_frag + (((size_t)bh * 128 + it * 2) * 64 + lane) * 8;
    int4 v0 = {(int)w[0], (int)w[1], (int)w[2], (int)w[3]};
    int4 v1 = {(int)w[4], (int)w[5], (int)w[6], (int)w[7]};
    *(int4*)fp = v0;
    *(int4*)(fp + 512) = v1;   // next jblk: +64 lanes * 8 shorts
  }
  float pel = 0.f, per = 0.f;
#pragma unroll
  for (int r = 0; r < 16; ++r) {
    int d = (r & 3) + 8 * (r >> 2) + 4 * kh;   // C/D row mapping (32x32 bf16)
    float hv = acc[r];
    pel = fmaf(hv, a[head * 2 * DK + d], pel);
    per = fmaf(hv, a[head * 2 * DK + DK + d], per);
  }
  pel += __shfl_xor(pel, 32);
  per += __shfl_xor(per, 32);
  if (kh == 0) {
    el[bh * N + n] = pel * LOG2E;
    float t = per * LOG2E;
    er2[bh * N + n] = exp2_fast(t);
    fr2[bh * N + n] = exp2_fast(0.2f * t);
  }
}

// ---------------- kernel 2: fused attention over a j-HALF ----------------
// grid = B*IT*2 = 512 (exactly 2 blocks/CU, fully resident, single round);
// block = 512 threads = 8 waves = (kq 0..1) x (head 0..3); each wave sweeps
// 512 j = 32 iters (p-loop x unrolled 16).
// r10 post-mortem: loop interior is ~62% stall; prime suspect is the 4
// top-of-iter ds_read broadcasts with immediate consumers (~120cy lgkm chain,
// same-phase across waves). Fix: 1-iter-ahead E/F register rotation (r9's
// structure) -- now viable because (512,2) gives >=128-VGPR headroom (the
// r9 attempt spilled only due to (512,4)'s 64-VGPR cap).
// s_setprio(1) around compute+MFMA cluster (HK/attn-proven small win).
__global__ __launch_bounds__(512, 2) void k_attn(const unsigned int* __restrict__ adjb,
                                                 const unsigned short* __restrict__ h_frag,
                                                 const float* __restrict__ el,
                                                 const float* __restrict__ er2,
                                                 const float* __restrict__ fr2,
                                                 float* __restrict__ pnum,
                                                 float* __restrict__ pden) {
  // 32KB, dual-role (barrier-separated): stage stg[t][head][j-local] during the
  // loop, partial slices part[kq][head][i*32+d] after it.
  __shared__ __align__(16) float smem[2][H][1024];
  __shared__ float lsh2[2][H][32];
  int blk = blockIdx.x;                 // 0..511
  int bit = blk >> 1, jh = blk & 1;
  int b = bit >> 6, it = bit & 63;
  int tid = threadIdx.x;
  int wave = tid >> 6;
  int head = wave & 3, kq = wave >> 2;
  int lane = tid & 63, lrow = lane & 31, kh = lane >> 5;
  int ig = it * 32 + lrow, bh = b * H + head;

  // stage er2/fr2 for this j-half, all 4 heads: 8192 floats, 4x float4/thread
#pragma unroll
  for (int i = 0; i < 4; ++i) {
    int q = tid + 512 * i;                    // float4 index, coalesced
    int t = q >> 10, hh = (q >> 8) & 3, jl = (q & 255) * 4;
    const float* src = (t ? fr2 : er2) + (b * H + hh) * N + jh * 1024 + jl;
    *(float4*)&smem[t][hh][jl] = *(const float4*)src;
  }

  float eli = el[bh * N + ig];
  float Eli = exp2_fast(eli);
  float Fli = exp2_fast(0.2f * eli);

  // wave's j-window: jh*1024 + kq*512, walked in 2 passes of 256 j.
  // coalesced fragment pointer: jblk = jh*64 + kq*32 + p*16 + s; 512 shorts/jblk
  const unsigned short* hp =
      h_frag + (((size_t)bh * 128 + jh * 64 + kq * 32) * 64 + lane) * 8;
  const unsigned int* abp0 = adjb + (size_t)(b * N + ig) * 64 + jh * 32 + kq * 16;
  int shkh = kh * 4;

  // h prefetch, 2 deep, live across passes (pass0 tail prefetches pass1 head)
  int4 hreg0 = *(const int4*)hp;
  int4 hreg1 = *(const int4*)(hp + 512);

  __syncthreads();   // stage visible

  v16f acc = {};
  float lsum = 0.f;
#pragma unroll 1
  for (int p = 0; p < 2; ++p) {
    const uint4* abp = (const uint4*)(abp0 + p * 8);
    uint4 ab0 = abp[0], ab1 = abp[1];
    unsigned adw[8] = {ab0.x, ab0.y, ab0.z, ab0.w, ab1.x, ab1.y, ab1.z, ab1.w};
    const unsigned short* hpp = hp + p * 8192;       // p*16 jblks * 512
    int jlb = kq * 512 + p * 256 + 4 * kh;           // j-local base (k-permuted)
    // E/F rotation: 1-iter-ahead LDS prefetch in registers (16 VGPRs)
    float4 Ea = *(const float4*)&smem[0][head][jlb];
    float4 Eb = *(const float4*)&smem[0][head][jlb + 8];
    float4 Fa = *(const float4*)&smem[1][head][jlb];
    float4 Fb = *(const float4*)&smem[1][head][jlb + 8];
#pragma unroll
    for (int s = 0; s < 16; ++s) {
      int4 hb = (s & 1) ? hreg1 : hreg0;
      if (p == 0 || s + 2 < 16) {          // pass1 tail: nothing left to prefetch
        int4 nv = *(const int4*)(hpp + (s + 2) * 512);
        if (s & 1) hreg1 = nv; else hreg0 = nv;
      }
      float4 ea = Ea, eb = Eb, fa = Fa, fb = Fb;
      if (s + 1 < 16) {
        Ea = *(const float4*)&smem[0][head][jlb + (s + 1) * 16];
        Eb = *(const float4*)&smem[0][head][jlb + (s + 1) * 16 + 8];
        Fa = *(const float4*)&smem[1][head][jlb + (s + 1) * 16];
        Fb = *(const float4*)&smem[1][head][jlb + (s + 1) * 16 + 8];
      }
      __builtin_amdgcn_s_setprio(1);
      // bits for slots e: j-offset = s*16 + 4*kh + (e&3) + 8*(e>>2)
      unsigned mb = (adw[s >> 1] >> (((s & 1) * 16) + shkh)) & 0xF0Fu;
      float ev[8] = {ea.x, ea.y, ea.z, ea.w, eb.x, eb.y, eb.z, eb.w};
      float fv[8] = {fa.x, fa.y, fa.z, fa.w, fb.x, fb.y, fb.z, fb.w};
      unsigned ub[8];
#pragma unroll
      for (int k = 0; k < 8; ++k) {
        float pv = fmaxf(Eli * ev[k], Fli * fv[k]);   // leaky-relu+exp, product form
        unsigned u = __builtin_bit_cast(unsigned, pv) & 0xFFFF0000u;
        // compile-time constant bit (k unrolled): {1,2,4,8,0x100,0x200,0x400,0x800}
        u = (mb & (1u << ((k & 3) + 8 * (k >> 2)))) ? u : 0u;
        ub[k] = u;
        lsum += __builtin_bit_cast(float, u); // truncated value: num/den consistent
      }
      unsigned u0 = __builtin_amdgcn_perm(ub[1], ub[0], 0x07060302u);
      unsigned u1 = __builtin_amdgcn_perm(ub[3], ub[2], 0x07060302u);
      unsigned u2 = __builtin_amdgcn_perm(ub[5], ub[4], 0x07060302u);
      unsigned u3 = __builtin_amdgcn_perm(ub[7], ub[6], 0x07060302u);
      uint4 au = {u0, u1, u2, u3};
      v8bf av = __builtin_bit_cast(v8bf, au);
      v8bf hv = __builtin_bit_cast(v8bf, hb);
      acc = __builtin_amdgcn_mfma_f32_32x32x16_bf16(av, hv, acc, 0, 0, 0);
      __builtin_amdgcn_s_setprio(0);
    }
  }

  lsum += __shfl_xor(lsum, 32);
  if (lane < 32) lsh2[kq][head][lane] = lsum;   // separate array: safe pre-barrier

  __syncthreads();   // all stage reads done before smem is reused as partials

#pragma unroll
  for (int r = 0; r < 16; ++r) {
    int rowl = (r & 3) + 8 * (r >> 2) + 4 * kh;   // i-row within tile
    smem[kq][head][rowl * 32 + lrow] = acc[r];    // private slice: plain store
  }
  __syncthreads();

  // combine 2 kq slices; 4096 partials / 512 threads = 8 floats (2x float4) each
  int e = tid * 8;
  int rh = e >> 10, rr = e & 1023;
  float4 a0 = *(const float4*)&smem[0][rh][rr];
  float4 a1 = *(const float4*)&smem[1][rh][rr];
  float4 b0 = *(const float4*)&smem[0][rh][rr + 4];
  float4 b1 = *(const float4*)&smem[1][rh][rr + 4];
  float4 s0 = {a0.x + a1.x, a0.y + a1.y, a0.z + a1.z, a0.w + a1.w};
  float4 s1 = {b0.x + b1.x, b0.y + b1.y, b0.z + b1.z, b0.w + b1.w};
  *(float4*)&pnum[(size_t)blk * 4096 + e] = s0;
  *(float4*)&pnum[(size_t)blk * 4096 + e + 4] = s1;
  if (tid < 128) {
    pden[blk * 128 + tid] = lsh2[0][tid >> 5][tid & 31] + lsh2[1][tid >> 5][tid & 31];
  }
}

// ---------------- kernel 3: combine j-halves + normalize ----------------
__global__ __launch_bounds__(1024) void k_final(const float* __restrict__ pnum,
                                                const float* __restrict__ pden,
                                                float* __restrict__ out) {
  int bit = blockIdx.x;            // 0..255 = (b, it)
  int b = bit >> 6, it = bit & 63;
  int tid = threadIdx.x;
  int e = tid * 4;
  int rh = e >> 10, ri = (e >> 5) & 31, rd = e & 31;
  size_t p0 = (size_t)(bit * 2) * 4096 + e;
  float4 n0 = *(const float4*)&pnum[p0];
  float4 n1 = *(const float4*)&pnum[p0 + 4096];
  float d = pden[bit * 2 * 128 + rh * 32 + ri] + pden[(bit * 2 + 1) * 128 + rh * 32 + ri];
  float inv = 1.0f / d;
  float4 o;
  o.x = (n0.x + n1.x) * inv;
  o.y = (n0.y + n1.y) * inv;
  o.z = (n0.z + n1.z) * inv;
  o.w = (n0.w + n1.w) * inv;
  *(float4*)&out[(size_t)((b * H + rh) * N + it * 32 + ri) * DK + rd] = o;
}

extern "C" void kernel_launch(void* const* d_in, const int* in_sizes, int n_in,
                              void* d_out, int out_size, void* d_ws, size_t ws_size,
                              hipStream_t stream) {
  const float* x = (const float*)d_in[0];
  const int* adj = (const int*)d_in[1];
  const float* W = (const float*)d_in[2];
  const float* a = (const float*)d_in[3];
  float* out = (float*)d_out;
  char* ws = (char*)d_ws;

  unsigned short* h_frag = (unsigned short*)(ws);          // 2 MB   [B*H][128 jblk][64][8]
  float* el = (float*)(ws + 0x200000);                     // 128 KB
  float* er2 = (float*)(ws + 0x220000);                    // 128 KB exp2 table
  float* fr2 = (float*)(ws + 0x240000);                    // 128 KB exp2(0.2) table
  unsigned short* wtb = (unsigned short*)(ws + 0x260000);  // 32 KB
  unsigned int* adjb = (unsigned int*)(ws + 0x270000);     // 2 MB bitmask
  unsigned short* xb = (unsigned short*)(ws + 0x470000);   // 2 MB
  float* pnum = (float*)(ws + 0x670000);                   // 8 MB   [512][4096]
  float* pden = (float*)(ws + 0xE70000);                   // 256 KB [512][128]
  // total ~15 MB

  hipLaunchKernelGGL(k_prep, dim3(PACK_BLOCKS + PREP_BLOCKS), dim3(256), 0, stream,
                     adj, x, W, adjb, xb, wtb);
  hipLaunchKernelGGL(k_hproj, dim3(B * IT), dim3(256), 0, stream, xb, wtb, a, h_frag, el, er2, fr2);
  hipLaunchKernelGGL(k_attn, dim3(B * IT * 2), dim3(512), 0, stream, adjb, h_frag, el, er2, fr2,
                     pnum, pden);
  hipLaunchKernelGGL(k_final, dim3(B * IT), dim3(1024), 0, stream, pnum, pden, out);
}